// Round 8
// baseline (442.727 us; speedup 1.0000x reference)
//
#include <hip/hip_runtime.h>
#include <stdint.h>

// Dims: msa[1,S,R,M] fp32 ; left_w/right_w[M,C] ; out_w[C*C,CZ] ; out[1,R,R,CZ] fp32
#define S_DIM 128
#define R_DIM 256
#define M_DIM 256
#define C_DIM 32
#define CZ_DIM 128
#define K2_DIM 1024  // C*C
#define NPROJ 256    // proj work items (one r each, both s-halves)
#define NFUSE 2048   // fuse tiles

typedef _Float16 f16;
typedef _Float16 f16x4 __attribute__((ext_vector_type(4)));
typedef _Float16 f16x8 __attribute__((ext_vector_type(8)));
typedef float f32x4 __attribute__((ext_vector_type(4)));
typedef float f32x16 __attribute__((ext_vector_type(16)));

typedef const __attribute__((address_space(1))) uint32_t gu32_t;
typedef __attribute__((address_space(3))) uint32_t lu32_t;
// async 16B global->LDS DMA; LDS dest = wave-uniform base + lane*16 (linear)
#define GLOAD_LDS16(g, l) \
    __builtin_amdgcn_global_load_lds((gu32_t*)(g), (lu32_t*)(l), 16, 0, 0)

// ---------------------------------------------------------------------------
// mega_kernel: plain (non-cooperative) launch, 2304 blocks x 512 threads.
// Dynamic work-grab: item = atomicAdd(ctr). Items 0..255 = proj rows (full
// block, both s-halves); 256.. = v8 fuse tiles gated on device-scope flags.
// Deadlock-free: resident capacity 512 blocks >= 256 proj items, and grabs
// are start-ordered, so all proj items run on the first wave of blocks.
// ctrl (in ws, memset per iteration): [0]=work ctr, [1]=wt2 ctr, [2..257]=flag[r].
// Producers: __threadfence() (device-scope L2 writeback) before flag set.
// Consumers: spin on device-scope atomicAdd(p,0), threadfence, then read.
// ---------------------------------------------------------------------------
__global__ __launch_bounds__(512, 4)
void mega_kernel(const float* __restrict__ msa, const float* __restrict__ lw,
                 const float* __restrict__ rw, const float* __restrict__ ow,
                 f16* __restrict__ left_t, f16* __restrict__ rt2,
                 f16* __restrict__ wt2, float* __restrict__ out,
                 unsigned* __restrict__ ctrl) {
    __shared__ __align__(16) char lds[65536];
    __shared__ int s_item;

    unsigned* wctr = ctrl + 1;
    unsigned* flag = ctrl + 2;   // flag[r], r in [0,256)

    int tid = threadIdx.x;
    if (tid == 0) s_item = (int)atomicAdd(ctrl, 1u);
    __syncthreads();
    int item = s_item;

    if (item < NPROJ) {
        // ================= proj item: r = item, both s-halves =================
        f16* wlT = (f16*)lds;            // 16 KB [mc][c][j]; later bounce buf
        f16* wrT = (f16*)(lds + 16384);  // 16 KB
        int w = tid >> 6, lane = tid & 63;
        int q = lane >> 4, li = lane & 15;
        int r = item;
        int sH = w >> 2;                 // s-half 0/1
        int s_col = sH * 64 + (w & 3) * 16 + li;

        // msa loads issued first — latency hides under stage A
        const f32x4* bp = (const f32x4*)(msa + ((size_t)s_col * R_DIM + r) * M_DIM + q * 8);
        f32x4 b[16];
#pragma unroll
        for (int ks = 0; ks < 8; ks++) { b[2*ks] = bp[ks*8]; b[2*ks+1] = bp[ks*8+1]; }

        // ---- wt2 slice EARLY + publish (fuse gates on wctr==NPROJ) ----
        {
            int i = item * 512 + tid;    // covers CZ*K2 = 256*512 exactly
            int cz = i >> 10, k2 = i & 1023;
            int c = k2 >> 5, e = k2 & 31;
            int k2p = ((e >> 2) << 7) + (c << 2) + (e & 3);
            int ntile = cz >> 5, l31o = cz & 31;
            int kk = k2p >> 4, q5o = (k2p >> 3) & 1, j = k2p & 7;
            wt2[(ntile * 64 + kk) * 512 + (l31o * 2 + q5o) * 8 + j] = (f16)ow[k2 * CZ_DIM + cz];
        }
        __threadfence();
        __syncthreads();
        if (tid == 0) atomicAdd(wctr, 1u);

        // ---- weight transpose-stage (512 threads) ----
#pragma unroll
        for (int k = 0; k < 16; k++) {
            int i = k * 512 + tid;       // i = m*32 + c
            int m = i >> 5, c = i & 31;
            int d = ((m >> 3) * 32 + c) * 8 + (m & 7);
            wlT[d] = (f16)lw[i];
            wrT[d] = (f16)rw[i];
        }
        __syncthreads();

        // ---- MFMA loop ----
        f32x4 aL0 = {0,0,0,0}, aL1 = {0,0,0,0}, aR0 = {0,0,0,0}, aR1 = {0,0,0,0};
#pragma unroll
        for (int ks = 0; ks < 8; ks++) {
            f16x8 bf;
#pragma unroll
            for (int u = 0; u < 4; u++) { bf[u] = (f16)b[2*ks][u]; bf[4+u] = (f16)b[2*ks+1][u]; }
            const f16* a0 = wlT + ((ks * 4 + q) * 32 + li) * 8;
            const f16* a1 = wrT + ((ks * 4 + q) * 32 + li) * 8;
            f16x8 al0 = *(const f16x8*)(a0);
            f16x8 al1 = *(const f16x8*)(a0 + 128);   // rows li+16
            f16x8 ar0 = *(const f16x8*)(a1);
            f16x8 ar1 = *(const f16x8*)(a1 + 128);
            aL0 = __builtin_amdgcn_mfma_f32_16x16x32_f16(al0, bf, aL0, 0, 0, 0);
            aL1 = __builtin_amdgcn_mfma_f32_16x16x32_f16(al1, bf, aL1, 0, 0, 0);
            aR0 = __builtin_amdgcn_mfma_f32_16x16x32_f16(ar0, bf, aR0, 0, 0, 0);
            aR1 = __builtin_amdgcn_mfma_f32_16x16x32_f16(ar1, bf, aR1, 0, 0, 0);
        }

        __syncthreads();   // staging reads done -> reuse wlT as bounce buffer
        f16* bL = wlT;            // [32 rows][128] f16 = 8 KB (full left image)
        f16* bR = wlT + 4096;     // [8 kl][512]  f16 = 8 KB (full rt2 image)
        {
            int sc7 = (s_col >> 3) & 7, sj = s_col & 7;
            int klg = s_col >> 4;            // 0..7
            int q5_s = (s_col >> 3) & 1;
#pragma unroll
            for (int reg = 0; reg < 4; reg++) {
                int c0 = q * 4 + reg;        // 0..15 ; (c0+16)&8 == c0&8 -> same H
                int o = ((sc7 ^ c0) & 7) * 8 + sj;
                int H = ((c0 & 8) >> 3) ^ sH;
                bL[c0 * 128 + H * 64 + o]        = (f16)aL0[reg];
                bL[(c0 + 16) * 128 + H * 64 + o] = (f16)aL1[reg];
                bR[klg * 512 + c0 * 16 + q5_s * 8 + sj]        = (f16)aR0[reg];
                bR[klg * 512 + (c0 + 16) * 16 + q5_s * 8 + sj] = (f16)aR1[reg];
            }
        }
        __syncthreads();   // bounce images complete

        // ---- coalesced stores: 512 threads x (16 B left + 16 B rt2) ----
        {
            f16* Lb = left_t + (size_t)(r >> 3) * 32768;
            int row = tid >> 4, col8 = tid & 15;
            *(f16x8*)(Lb + ((r & 7) * 32 + row) * 128 + col8 * 8) =
                *(const f16x8*)(bL + row * 128 + col8 * 8);
            int ck = tid >> 6, ix = tid & 63;
            *(f16x8*)(rt2 + (size_t)(r * 8 + ck) * 512 + ix * 8) =
                *(const f16x8*)(bR + ck * 512 + ix * 8);
        }
        __threadfence();   // device-scope release (L2 writeback)
        __syncthreads();
        if (tid == 0) atomicAdd(&flag[r], 1u);
        return;
    }

    // ===================== fuse tile (v8 body, gated) =====================
    int it2 = item - NPROJ;
    int bid = (it2 & 7) * 256 + (it2 >> 3);   // bijective XCD swizzle (2048=8*256)
    int br = bid >> 6, bt = bid & 63;
    int w = tid >> 6, lane = tid & 63;
    int q5 = lane >> 5, l31 = lane & 31, lx = lane & 15;

    // ---- spin on producers: wt2 complete + the 12 needed r-rows ----
    if (tid == 0) {
        while (atomicAdd(wctr, 0u) < NPROJ) __builtin_amdgcn_s_sleep(2);
#pragma unroll 1
        for (int k = 0; k < 8; k++)
            while (atomicAdd(&flag[br * 8 + k], 0u) == 0u) __builtin_amdgcn_s_sleep(2);
#pragma unroll 1
        for (int k = 0; k < 4; k++)
            while (atomicAdd(&flag[bt * 4 + k], 0u) == 0u) __builtin_amdgcn_s_sleep(2);
        __threadfence();   // acquire: invalidate stale L1/L2 view
    }
    __syncthreads();

    f16* Ls = (f16*)lds;
    const f16* Lg = left_t + (size_t)br * 32768;    // pre-swizzled LDS image

    // ---- phase 0: async stage left (8 x 16B DMA per thread) ----
#pragma unroll
    for (int it = 0; it < 8; it++) {
        GLOAD_LDS16(Lg + (size_t)(it * 512 + tid) * 8, Ls + (it * 512 + tid) * 8);
    }

    // afr prefetch (coalesced fragment-major) — overlaps the DMA
    int t_tile = w & 3, rg4 = w >> 2;
    int g = bt * 4 + t_tile;
    const f16* ap = rt2 + (size_t)g * 4096 + (l31 * 2 + q5) * 8;
    f16x8 afr[8];
#pragma unroll
    for (int ks = 0; ks < 8; ks++) afr[ks] = *(const f16x8*)(ap + ks * 512);

    __syncthreads();   // drains vmcnt → LDS stage complete

    // ---- phase 1: stage1 MFMAs (D[te][rc]) ----
    f32x16 acc[4] = {};
    __builtin_amdgcn_s_setprio(1);
#pragma unroll
    for (int i = 0; i < 4; i++) {
        const f16* bbase = Ls + ((rg4 * 4 + i) * 32 + l31) * 128;
#pragma unroll
        for (int ks = 0; ks < 8; ks++) {
            f16x8 bfr = *(const f16x8*)(bbase + (((2 * ks + q5) ^ lx) << 3));
            acc[i] = __builtin_amdgcn_mfma_f32_32x32x16_f16(afr[ks], bfr, acc[i], 0, 0, 0);
        }
    }
    __builtin_amdgcn_s_setprio(0);

    // ---- W group 0: issue pre-barrier (hidden by phase 2 + barrier) ----
    int kh = w >> 2;
    const f16* wbase = wt2 + (size_t)(t_tile * 64 + kh * 32) * 512 + (l31 * 2 + q5) * 8;
    f16x8 wfg[8][4];
#pragma unroll
    for (int u = 0; u < 4; u++) wfg[0][u] = *(const f16x8*)(wbase + u * 512);

    __syncthreads();   // protects LDS overlay (phase2 writes over Ls)

    // ---- phase 2: write outer to LDS ----
    int chc = l31 >> 1, bsub = 8 * (l31 & 1);
#pragma unroll
    for (int i = 0; i < 4; i++) {
        int p = (rg4 * 4 + i) * 4 + t_tile;         // pair row 0..31
        char* prow = lds + p * 2048;
#pragma unroll
        for (int rg = 0; rg < 4; rg++) {
            int ch = (2 * rg + q5) * 16 + chc;
            int phys = (ch + p) & 127;
            f16x4 h = {(f16)acc[i][4 * rg], (f16)acc[i][4 * rg + 1],
                       (f16)acc[i][4 * rg + 2], (f16)acc[i][4 * rg + 3]};
            *(f16x4*)(prow + phys * 16 + bsub) = h;
        }
    }
    __syncthreads();

    // ---- phase 3: stage2, fully unrolled, 3-deep W ring + 2-deep af ring ----
    const char* lbase = lds + l31 * 2048;           // p = l31 (2048-aligned rows)
    int base = 64 * kh + q5 + l31;                  // k-chunk index before wrap
    f16x8 afg[8][4];
    f32x16 accA = {}, accB = {};
    __builtin_amdgcn_s_setprio(1);
#pragma unroll
    for (int gg = 0; gg < 8; gg++) {
        if (gg == 0) {
#pragma unroll
            for (int u = 0; u < 4; u++) wfg[1][u] = *(const f16x8*)(wbase + (4 + u) * 512);
#pragma unroll
            for (int u = 0; u < 4; u++) wfg[2][u] = *(const f16x8*)(wbase + (8 + u) * 512);
#pragma unroll
            for (int u = 0; u < 4; u++)
                afg[0][u] = *(const f16x8*)(lbase + (((base + 2 * u) & 127) << 4));
#pragma unroll
            for (int u = 0; u < 4; u++)
                afg[1][u] = *(const f16x8*)(lbase + (((base + 8 + 2 * u) & 127) << 4));
        } else {
            if (gg + 2 < 8) {
#pragma unroll
                for (int u = 0; u < 4; u++)
                    wfg[gg + 2][u] = *(const f16x8*)(wbase + ((gg + 2) * 4 + u) * 512);
            }
            if (gg + 1 < 8) {
#pragma unroll
                for (int u = 0; u < 4; u++)
                    afg[gg + 1][u] = *(const f16x8*)(lbase + (((base + (gg + 1) * 8 + 2 * u) & 127) << 4));
            }
        }
        accA = __builtin_amdgcn_mfma_f32_32x32x16_f16(afg[gg][0], wfg[gg][0], accA, 0, 0, 0);
        accB = __builtin_amdgcn_mfma_f32_32x32x16_f16(afg[gg][1], wfg[gg][1], accB, 0, 0, 0);
        accA = __builtin_amdgcn_mfma_f32_32x32x16_f16(afg[gg][2], wfg[gg][2], accA, 0, 0, 0);
        accB = __builtin_amdgcn_mfma_f32_32x32x16_f16(afg[gg][3], wfg[gg][3], accB, 0, 0, 0);
    }
    __builtin_amdgcn_s_setprio(0);
    f32x16 acc2;
#pragma unroll
    for (int v = 0; v < 16; v++) acc2[v] = accA[v] + accB[v];
    __syncthreads();

    // ---- k-reduction: wave w+4 -> LDS, wave w adds ----
    if (w >= 4) {
        char* rb = lds + (w - 4) * 4096 + lane * 64;
#pragma unroll
        for (int u = 0; u < 4; u++) {
            f32x4 part = {acc2[4 * u], acc2[4 * u + 1], acc2[4 * u + 2], acc2[4 * u + 3]};
            *(f32x4*)(rb + u * 16) = part;
        }
    }
    __syncthreads();
    if (w < 4) {
        const char* rb = lds + w * 4096 + lane * 64;
#pragma unroll
        for (int u = 0; u < 4; u++) {
            f32x4 part = *(const f32x4*)(rb + u * 16);
#pragma unroll
            for (int v = 0; v < 4; v++) acc2[4 * u + v] += part[v];
        }
        // store: D row = p = (reg&3)+8*(reg>>2)+4*q5 ; col = cz = w*32 + l31
        int r0 = br * 8, t0 = bt * 4, cz = w * 32 + l31;
#pragma unroll
        for (int reg = 0; reg < 16; reg++) {
            int p = (reg & 3) + 8 * (reg >> 2) + 4 * q5;
            out[((size_t)((r0 + (p >> 2)) * R_DIM + t0 + (p & 3))) * CZ_DIM + cz] = acc2[reg];
        }
    }
}

// ---------------------------------------------------------------------------
extern "C" void kernel_launch(void* const* d_in, const int* in_sizes, int n_in,
                              void* d_out, int out_size, void* d_ws, size_t ws_size,
                              hipStream_t stream) {
    const float* msa = (const float*)d_in[0];
    const float* lw  = (const float*)d_in[1];
    const float* rw  = (const float*)d_in[2];
    const float* ow  = (const float*)d_in[3];
    char* ws = (char*)d_ws;
    f16* left_t = (f16*)(ws);                                   // 2 MB (pre-swizzled)
    f16* rt2    = (f16*)(ws + (size_t)2 * 1024 * 1024);         // 2 MB
    f16* wt2    = (f16*)(ws + (size_t)4 * 1024 * 1024);         // 256 KB
    unsigned* ctrl = (unsigned*)(ws + (size_t)4 * 1024 * 1024 + 262144); // 4 KB
    float* out  = (float*)d_out;

    // zero the control block each iteration (captured in the graph -> replayed)
    hipMemsetAsync(ctrl, 0, 4096, stream);
    mega_kernel<<<dim3(NPROJ + NFUSE), dim3(512), 0, stream>>>(
        msa, lw, rw, ow, left_t, rt2, wt2, out, ctrl);
}